// Round 1
// baseline (967.688 us; speedup 1.0000x reference)
//
#include <hip/hip_runtime.h>
#include <math.h>

#define N_NODES 50000
#define N_EDGES 800000
#define NB 32
#define NA 128

constexpr double STEP_D = 10.0 / 31.0;
constexpr float  STEP_F = (float)(10.0 / 31.0);       // matches np.float32 width
constexpr float  COEFF  = -0.5f / (STEP_F * STEP_F);  // -0.5/width^2
constexpr float  R2     = 1.41421356237309515f;       // sqrt(2) = PREF2 for mixed terms

__device__ __forceinline__ float silu_f(float x) {
    return x / (1.0f + __expf(-x));
}

// ---------------- K0: transpose cj_w1 and msg_w2 ----------------
__global__ void k_transpose(const float* __restrict__ cj_w1,
                            const float* __restrict__ msg_w2,
                            float* __restrict__ w1t, float* __restrict__ mw2t) {
    int id = blockIdx.x * 256 + threadIdx.x;  // 16384 total
    int j = id >> 7, k = id & 127;
    w1t[j * 128 + k]  = cj_w1[k * 128 + j];
    mw2t[j * 128 + k] = msg_w2[k * 128 + j];
}

// ---------------- K1: cj = MLP(feat) -> [N] scalar ----------------
__global__ __launch_bounds__(64) void k_cj(const float* __restrict__ feat,
                                           const float* __restrict__ w1t,
                                           const float* __restrict__ b1,
                                           const float* __restrict__ w2,
                                           const float* __restrict__ b2,
                                           float* __restrict__ cj) {
    int n = blockIdx.x * 64 + threadIdx.x;
    if (n >= N_NODES) return;
    float f[128];
    const float4* fr = (const float4*)(feat + (size_t)n * 128);
#pragma unroll
    for (int u = 0; u < 32; u++) {
        float4 v = fr[u];
        f[4 * u] = v.x; f[4 * u + 1] = v.y; f[4 * u + 2] = v.z; f[4 * u + 3] = v.w;
    }
    float acc = b2[0];
    for (int j = 0; j < 128; j++) {
        const float* wr = w1t + j * 128;  // row of transposed w1 (uniform -> s_load)
        float a0 = b1[j], a1 = 0.f, a2 = 0.f, a3 = 0.f;
#pragma unroll
        for (int k = 0; k < 128; k += 4) {
            a0 = fmaf(f[k], wr[k], a0);
            a1 = fmaf(f[k + 1], wr[k + 1], a1);
            a2 = fmaf(f[k + 2], wr[k + 2], a2);
            a3 = fmaf(f[k + 3], wr[k + 3], a3);
        }
        float h = (a0 + a1) + (a2 + a3);
        acc = fmaf(silu_f(h), w2[j], acc);
    }
    cj[n] = acc;
}

// ---------------- K3a: count edges per src node ----------------
__global__ void k_count(const int* __restrict__ src, int* __restrict__ cnt) {
    int e = blockIdx.x * 256 + threadIdx.x;
    if (e < N_EDGES) atomicAdd(&cnt[src[e]], 1);
}

// ---------------- K3b: two-level exclusive scan ----------------
__global__ void k_scan1(const int* __restrict__ cnt, int* __restrict__ offs,
                        int* __restrict__ bsum) {
    __shared__ int s[1024];
    int i = blockIdx.x * 1024 + threadIdx.x;
    int v = (i < N_NODES) ? cnt[i] : 0;
    s[threadIdx.x] = v;
    __syncthreads();
    for (int o = 1; o < 1024; o <<= 1) {
        int t = (threadIdx.x >= (unsigned)o) ? s[threadIdx.x - o] : 0;
        __syncthreads();
        s[threadIdx.x] += t;
        __syncthreads();
    }
    if (i < N_NODES) offs[i] = s[threadIdx.x] - v;  // exclusive within block
    if (threadIdx.x == 1023) bsum[blockIdx.x] = s[1023];
}

__global__ void k_scan2(const int* __restrict__ bsum, int* __restrict__ bbase, int nb) {
    if (threadIdx.x == 0) {
        int r = 0;
        for (int i = 0; i < nb; i++) { bbase[i] = r; r += bsum[i]; }
    }
}

__global__ void k_scan3(int* __restrict__ offs, const int* __restrict__ bbase,
                        int* __restrict__ cursor) {
    int i = blockIdx.x * 1024 + threadIdx.x;
    if (i < N_NODES) {
        int v = offs[i] + bbase[blockIdx.x];
        offs[i] = v;
        cursor[i] = v;
    }
}

// ---------------- K3c: scatter edge ids into per-node lists ----------------
__global__ void k_scatter(const int* __restrict__ src, int* __restrict__ cursor,
                          int* __restrict__ elist) {
    int e = blockIdx.x * 256 + threadIdx.x;
    if (e < N_EDGES) {
        int p = atomicAdd(&cursor[src[e]], 1);
        elist[p] = e;
    }
}

// ---------------- K4: per-node aggregation (wave per node) ----------------
// lane: b = lane>>1 (basis), th = lane&1 selects t-triple {0,1,2} or {3,4,5}
__global__ __launch_bounds__(256) void k_agg(const float* __restrict__ dis_vec,
                                             const int* __restrict__ dst,
                                             const int* __restrict__ elist,
                                             const int* __restrict__ offs,
                                             const int* __restrict__ cnt,
                                             const float* __restrict__ cj,
                                             float* __restrict__ msg_in) {
    int lane = threadIdx.x & 63;
    int n = blockIdx.x * 4 + (threadIdx.x >> 6);
    n = __builtin_amdgcn_readfirstlane(n);
    if (n >= N_NODES) return;
    int b = lane >> 1, th = lane & 1;
    float offb = (float)((double)b * STEP_D);
    int beg = offs[n];
    int deg = cnt[n];
    float a0 = 0.f, a1 = 0.f, a2 = 0.f;
    for (int i = 0; i < deg; i++) {
        int e = elist[beg + i];
        e = __builtin_amdgcn_readfirstlane(e);
        int d = dst[e];
        d = __builtin_amdgcn_readfirstlane(d);
        float cjd = cj[d];
        float dx = dis_vec[3 * e], dy = dis_vec[3 * e + 1], dz = dis_vec[3 * e + 2];
        float ax = dx + 1e-9f, ay = dy + 1e-9f, az = dz + 1e-9f;
        float dis = sqrtf(ax * ax + ay * ay + az * az);
        float x = dx + 1e-8f, y = dy + 1e-8f, z = dz + 1e-8f;
        float dd = dis - offb;
        float g = __expf(COEFF * dd * dd) * cjd;
        // prefactor * PREF2 for this lane's 3 t values
        float w0 = th ? x * z * R2 : z * z;       // t=3:(1,0,1)  | t=0:(0,0,2)
        float w1 = th ? x * y * R2 : y * z * R2;  // t=4:(1,1,0)  | t=1:(0,1,1)
        float w2 = th ? x * x : y * y;            // t=5:(2,0,0)  | t=2:(0,2,0)
        a0 = fmaf(g, w0, a0);
        a1 = fmaf(g, w1, a1);
        a2 = fmaf(g, w2, a2);
    }
    float s = a0 * a0 + a1 * a1 + a2 * a2;
    float f2 = s + __shfl_xor(s, 1, 64);  // sum over all 6 t
    float p = f2 + 1e-9f;
    p = p * p;
    float tot = p;
#pragma unroll
    for (int m = 1; m < 64; m <<= 1) tot += __shfl_xor(tot, m, 64);
    // each b counted twice (both th lanes) -> halve
    float nrm = sqrtf(0.5f * tot);
    float val = f2 / (nrm + 1.0f);
    if (th == 0) msg_in[(size_t)n * NB + b] = val;
}

// ---------------- K5: msg MLP (thread per node) ----------------
__global__ __launch_bounds__(64) void k_msg(const float* __restrict__ msg_in,
                                            const float* __restrict__ w1,   // [32,128] original
                                            const float* __restrict__ b1,
                                            const float* __restrict__ w2t,  // [128,128] transposed
                                            const float* __restrict__ b2,
                                            float* __restrict__ out) {
    __shared__ float mi[32 * 64];
    int tid = threadIdx.x;
    int n = blockIdx.x * 64 + tid;
    bool act = n < N_NODES;
    const float4* mr = (const float4*)(msg_in + (size_t)(act ? n : 0) * 32);
#pragma unroll
    for (int u = 0; u < 8; u++) {
        float4 v = act ? mr[u] : float4{0.f, 0.f, 0.f, 0.f};
        mi[(4 * u + 0) * 64 + tid] = v.x;
        mi[(4 * u + 1) * 64 + tid] = v.y;
        mi[(4 * u + 2) * 64 + tid] = v.z;
        mi[(4 * u + 3) * 64 + tid] = v.w;
    }
    float h[128];
#pragma unroll
    for (int j = 0; j < 128; j++) h[j] = b1[j];
    for (int b = 0; b < 32; b++) {
        float m = mi[b * 64 + tid];
        const float* wr = w1 + b * 128;  // contiguous row, uniform -> s_load
#pragma unroll
        for (int j = 0; j < 128; j++) h[j] = fmaf(m, wr[j], h[j]);
    }
#pragma unroll
    for (int j = 0; j < 128; j++) h[j] = silu_f(h[j]);
    if (!act) return;
    float* orow = out + (size_t)n * 128;
    for (int j = 0; j < 128; j++) {
        const float* wr = w2t + j * 128;
        float a0 = 0.f, a1 = 0.f, a2 = 0.f, a3 = 0.f;
#pragma unroll
        for (int k = 0; k < 128; k += 4) {
            a0 = fmaf(h[k], wr[k], a0);
            a1 = fmaf(h[k + 1], wr[k + 1], a1);
            a2 = fmaf(h[k + 2], wr[k + 2], a2);
            a3 = fmaf(h[k + 3], wr[k + 3], a3);
        }
        orow[j] = b2[j] + ((a0 + a1) + (a2 + a3));
    }
}

// ---------------- K2: filt (thread per edge) ----------------
__global__ __launch_bounds__(256) void k_filt(const float* __restrict__ dis_vec,
                                              const float* __restrict__ fw1,
                                              const float* __restrict__ fw2,
                                              const float* __restrict__ fb2,
                                              float* __restrict__ out) {
    int e = blockIdx.x * 256 + threadIdx.x;
    if (e >= N_EDGES) return;
    float dx = dis_vec[3 * e], dy = dis_vec[3 * e + 1], dz = dis_vec[3 * e + 2];
    float ax = dx + 1e-9f, ay = dy + 1e-9f, az = dz + 1e-9f;
    float dis = sqrtf(ax * ax + ay * ay + az * az);
    float x = dx + 1e-8f, y = dy + 1e-8f, z = dz + 1e-8f;
    // prefactor * PREF2, t order: (0,0,2),(0,1,1),(0,2,0),(1,0,1),(1,1,0),(2,0,0)
    float pre[6];
    pre[0] = z * z;      pre[1] = y * z * R2; pre[2] = y * y;
    pre[3] = x * z * R2; pre[4] = x * y * R2; pre[5] = x * x;
    float A = 0.f, B = 0.f;
#pragma unroll
    for (int t = 0; t < 6; t++) { A = fmaf(pre[t], pre[t], A); B += pre[t]; }
    float q[6];
#pragma unroll
    for (int tp = 0; tp < 6; tp++) {
        float s = 0.f;
#pragma unroll
        for (int t = 0; t < 6; t++) s = fmaf(pre[t], fw1[t * 6 + tp], s);
        q[tp] = s;
    }
    float bias = fb2[0];
    float w2r[6];
#pragma unroll
    for (int t = 0; t < 6; t++) w2r[t] = fw2[t];
    float* orow = out + (size_t)e * 32;
    for (int b4 = 0; b4 < 32; b4 += 4) {
        float ob[4];
#pragma unroll
        for (int u = 0; u < 4; u++) {
            int b = b4 + u;
            float offb = (float)((double)b * STEP_D);
            float dd = dis - offb;
            float g = __expf(COEFF * dd * dd);
            // ||gauss + 1e-8||^2 over t, expanded: g^2*A + 2e-8*g*B + 6e-16
            float ns = fmaf(g * g, A, fmaf(2e-8f * g, B, 6e-16f));
            float rn = 1.0f / (sqrtf(ns) + 1.0f);
            float s = g * rn;
            float o = bias;
#pragma unroll
            for (int tp = 0; tp < 6; tp++) o = fmaf(silu_f(s * q[tp]), w2r[tp], o);
            ob[u] = o;
        }
        ((float4*)orow)[b4 >> 2] = make_float4(ob[0], ob[1], ob[2], ob[3]);
    }
}

extern "C" void kernel_launch(void* const* d_in, const int* in_sizes, int n_in,
                              void* d_out, int out_size, void* d_ws, size_t ws_size,
                              hipStream_t stream) {
    (void)in_sizes; (void)n_in; (void)out_size; (void)ws_size;
    const float* feat    = (const float*)d_in[0];
    const float* dis_vec = (const float*)d_in[1];
    const float* cj_w1   = (const float*)d_in[2];
    const float* cj_b1   = (const float*)d_in[3];
    const float* cj_w2   = (const float*)d_in[4];
    const float* cj_b2   = (const float*)d_in[5];
    const float* msg_w1  = (const float*)d_in[6];
    const float* msg_b1  = (const float*)d_in[7];
    const float* msg_w2  = (const float*)d_in[8];
    const float* msg_b2  = (const float*)d_in[9];
    const float* filt_w1 = (const float*)d_in[10];
    const float* filt_w2 = (const float*)d_in[11];
    const float* filt_b2 = (const float*)d_in[12];
    const int*   src     = (const int*)d_in[13];
    const int*   dst     = (const int*)d_in[14];
    float* out = (float*)d_out;

    // workspace layout (elements), all 16B aligned
    float* ws     = (float*)d_ws;
    float* cj     = ws;                    // 50048
    float* msg_in = cj + 50048;            // 1600000
    float* w1t    = msg_in + 1600000;      // 16384
    float* mw2t   = w1t + 16384;           // 16384
    int*   cnt    = (int*)(mw2t + 16384);  // 50048
    int*   offs   = cnt + 50048;           // 50048
    int*   cursor = offs + 50048;          // 50048
    int*   bsum   = cursor + 50048;        // 64
    int*   bbase  = bsum + 64;             // 64
    int*   elist  = bbase + 64;            // 800000
    // total ~10.5 MB

    hipMemsetAsync(cnt, 0, N_NODES * sizeof(int), stream);

    k_transpose<<<64, 256, 0, stream>>>(cj_w1, msg_w2, w1t, mw2t);
    k_cj<<<(N_NODES + 63) / 64, 64, 0, stream>>>(feat, w1t, cj_b1, cj_w2, cj_b2, cj);
    k_count<<<(N_EDGES + 255) / 256, 256, 0, stream>>>(src, cnt);
    k_scan1<<<49, 1024, 0, stream>>>(cnt, offs, bsum);
    k_scan2<<<1, 64, 0, stream>>>(bsum, bbase, 49);
    k_scan3<<<49, 1024, 0, stream>>>(offs, bbase, cursor);
    k_scatter<<<(N_EDGES + 255) / 256, 256, 0, stream>>>(src, cursor, elist);
    k_agg<<<N_NODES / 4, 256, 0, stream>>>(dis_vec, dst, elist, offs, cnt, cj, msg_in);
    k_msg<<<(N_NODES + 63) / 64, 64, 0, stream>>>(msg_in, msg_w1, msg_b1, mw2t, msg_b2, out);
    k_filt<<<(N_EDGES + 255) / 256, 256, 0, stream>>>(dis_vec, filt_w1, filt_w2, filt_b2,
                                                      out + (size_t)N_NODES * NA);
}

// Round 2
// 561.775 us; speedup vs baseline: 1.7226x; 1.7226x over previous
//
#include <hip/hip_runtime.h>
#include <math.h>

#define N_NODES 50000
#define N_EDGES 800000
#define NB 32
#define NA 128

constexpr double STEP_D = 10.0 / 31.0;
constexpr float  STEP_F = (float)(10.0 / 31.0);       // matches np.float32 width
constexpr float  COEFF  = -0.5f / (STEP_F * STEP_F);  // -0.5/width^2
constexpr float  R2     = 1.41421356237309515f;       // sqrt(2) = PREF2 for mixed terms

__device__ __forceinline__ float silu_f(float x) {
    return x / (1.0f + __expf(-x));
}

// ---------------- K1: cj = MLP(feat) -> [N] scalar ----------------
// Tiled: block=256 (4 waves), 32 nodes/block, thread = output column j for 16 nodes.
__global__ __launch_bounds__(256) void k_cj(const float* __restrict__ feat,
                                            const float* __restrict__ w1,   // [128,128] orig
                                            const float* __restrict__ b1,
                                            const float* __restrict__ w2,   // [128,1]
                                            const float* __restrict__ b2,
                                            float* __restrict__ cj) {
    __shared__ float fls[32 * 128];   // 16 KB feat tile
    __shared__ float red[2][32];
    int tid  = threadIdx.x;
    int lane = tid & 63;
    int wave = tid >> 6;         // 0..3
    int jh   = wave & 1;         // j half
    int nh   = wave >> 1;        // node half
    int j    = jh * 64 + lane;   // 0..127
    int n0   = blockIdx.x * 32;

    // stage feat tile (coalesced float4, clamped for tail block)
    {
        const float4* fp = (const float4*)feat;
        int base = n0 * 32;                    // float4 index
        int maxi = N_NODES * 32 - 1;
#pragma unroll
        for (int r = 0; r < 4; r++) {
            int idx = base + r * 256 + tid;
            ((float4*)fls)[r * 256 + tid] = fp[min(idx, maxi)];
        }
    }
    __syncthreads();

    float h[16];
#pragma unroll
    for (int i = 0; i < 16; i++) h[i] = b1[j];
    for (int kb = 0; kb < 128; kb += 4) {
        float wv[4];
#pragma unroll
        for (int u = 0; u < 4; u++) wv[u] = w1[(kb + u) * 128 + j];
#pragma unroll
        for (int i = 0; i < 16; i++) {
            float4 f4 = *(const float4*)&fls[(nh * 16 + i) * 128 + kb];
            h[i] = fmaf(f4.x, wv[0], h[i]);
            h[i] = fmaf(f4.y, wv[1], h[i]);
            h[i] = fmaf(f4.z, wv[2], h[i]);
            h[i] = fmaf(f4.w, wv[3], h[i]);
        }
    }
    // epilogue: cj[n] = b2 + sum_j silu(h)*w2[j]
    float w2j = w2[j];
    float keep = 0.f;
#pragma unroll
    for (int i = 0; i < 16; i++) {
        float v = silu_f(h[i]) * w2j;
#pragma unroll
        for (int m = 1; m < 64; m <<= 1) v += __shfl_xor(v, m, 64);
        if (lane == i) keep = v;
    }
    if (lane < 16) red[jh][nh * 16 + lane] = keep;
    __syncthreads();
    if (tid < 32) {
        int n = n0 + tid;
        if (n < N_NODES) cj[n] = b2[0] + red[0][tid] + red[1][tid];
    }
}

// ---------------- K3a: count edges per src node ----------------
__global__ void k_count(const int* __restrict__ src, int* __restrict__ cnt) {
    int e = blockIdx.x * 256 + threadIdx.x;
    if (e < N_EDGES) atomicAdd(&cnt[src[e]], 1);
}

// ---------------- K3b: two-level exclusive scan ----------------
__global__ void k_scan1(const int* __restrict__ cnt, int* __restrict__ offs,
                        int* __restrict__ bsum) {
    __shared__ int s[1024];
    int i = blockIdx.x * 1024 + threadIdx.x;
    int v = (i < N_NODES) ? cnt[i] : 0;
    s[threadIdx.x] = v;
    __syncthreads();
    for (int o = 1; o < 1024; o <<= 1) {
        int t = (threadIdx.x >= (unsigned)o) ? s[threadIdx.x - o] : 0;
        __syncthreads();
        s[threadIdx.x] += t;
        __syncthreads();
    }
    if (i < N_NODES) offs[i] = s[threadIdx.x] - v;  // exclusive within block
    if (threadIdx.x == 1023) bsum[blockIdx.x] = s[1023];
}

__global__ void k_scan2(const int* __restrict__ bsum, int* __restrict__ bbase, int nb) {
    if (threadIdx.x == 0) {
        int r = 0;
        for (int i = 0; i < nb; i++) { bbase[i] = r; r += bsum[i]; }
    }
}

__global__ void k_scan3(int* __restrict__ offs, const int* __restrict__ bbase,
                        int* __restrict__ cursor) {
    int i = blockIdx.x * 1024 + threadIdx.x;
    if (i < N_NODES) {
        int v = offs[i] + bbase[blockIdx.x];
        offs[i] = v;
        cursor[i] = v;
    }
}

// ---------------- K3c: scatter edge ids into per-node lists ----------------
__global__ void k_scatter(const int* __restrict__ src, int* __restrict__ cursor,
                          int* __restrict__ elist) {
    int e = blockIdx.x * 256 + threadIdx.x;
    if (e < N_EDGES) {
        int p = atomicAdd(&cursor[src[e]], 1);
        elist[p] = e;
    }
}

// ---------------- K4: per-node aggregation (wave per node) ----------------
// lane: b = lane>>1 (basis), th = lane&1 selects t-triple {0,1,2} or {3,4,5}
__global__ __launch_bounds__(256) void k_agg(const float* __restrict__ dis_vec,
                                             const int* __restrict__ dst,
                                             const int* __restrict__ elist,
                                             const int* __restrict__ offs,
                                             const int* __restrict__ cnt,
                                             const float* __restrict__ cj,
                                             float* __restrict__ msg_in) {
    int lane = threadIdx.x & 63;
    int n = blockIdx.x * 4 + (threadIdx.x >> 6);
    n = __builtin_amdgcn_readfirstlane(n);
    if (n >= N_NODES) return;
    int b = lane >> 1, th = lane & 1;
    float offb = (float)((double)b * STEP_D);
    int beg = offs[n];
    int deg = cnt[n];
    float a0 = 0.f, a1 = 0.f, a2 = 0.f;
    for (int i = 0; i < deg; i++) {
        int e = elist[beg + i];
        e = __builtin_amdgcn_readfirstlane(e);
        int d = dst[e];
        d = __builtin_amdgcn_readfirstlane(d);
        float cjd = cj[d];
        float dx = dis_vec[3 * e], dy = dis_vec[3 * e + 1], dz = dis_vec[3 * e + 2];
        float ax = dx + 1e-9f, ay = dy + 1e-9f, az = dz + 1e-9f;
        float dis = sqrtf(ax * ax + ay * ay + az * az);
        float x = dx + 1e-8f, y = dy + 1e-8f, z = dz + 1e-8f;
        float dd = dis - offb;
        float g = __expf(COEFF * dd * dd) * cjd;
        // prefactor * PREF2 for this lane's 3 t values
        float w0 = th ? x * z * R2 : z * z;       // t=3:(1,0,1)  | t=0:(0,0,2)
        float w1 = th ? x * y * R2 : y * z * R2;  // t=4:(1,1,0)  | t=1:(0,1,1)
        float w2 = th ? x * x : y * y;            // t=5:(2,0,0)  | t=2:(0,2,0)
        a0 = fmaf(g, w0, a0);
        a1 = fmaf(g, w1, a1);
        a2 = fmaf(g, w2, a2);
    }
    float s = a0 * a0 + a1 * a1 + a2 * a2;
    float f2 = s + __shfl_xor(s, 1, 64);  // sum over all 6 t
    float p = f2 + 1e-9f;
    p = p * p;
    float tot = p;
#pragma unroll
    for (int m = 1; m < 64; m <<= 1) tot += __shfl_xor(tot, m, 64);
    // each b counted twice (both th lanes) -> halve
    float nrm = sqrtf(0.5f * tot);
    float val = f2 / (nrm + 1.0f);
    if (th == 0) msg_in[(size_t)n * NB + b] = val;
}

// ---------------- K5: msg MLP, tiled (32 nodes/block, 256 threads) ----------------
__global__ __launch_bounds__(256) void k_msg(const float* __restrict__ msg_in,
                                             const float* __restrict__ w1,   // [32,128] orig
                                             const float* __restrict__ b1,
                                             const float* __restrict__ w2,   // [128,128] orig
                                             const float* __restrict__ b2,
                                             float* __restrict__ out) {
    __shared__ float mi[32 * 32];     // 4 KB input tile
    __shared__ float sh[32 * 128];    // 16 KB hidden tile
    int tid  = threadIdx.x;
    int lane = tid & 63;
    int wave = tid >> 6;
    int jh   = wave & 1;
    int nh   = wave >> 1;
    int j    = jh * 64 + lane;
    int n0   = blockIdx.x * 32;

    // stage msg_in tile (32 nodes x 32 basis = 1024 floats)
    {
        const float4* srcp = (const float4*)msg_in;
        int idx = n0 * 8 + tid;                  // float4 index
        int maxi = N_NODES * 8 - 1;
        ((float4*)mi)[tid] = srcp[min(idx, maxi)];
    }
    __syncthreads();

    float h[16];
#pragma unroll
    for (int i = 0; i < 16; i++) h[i] = b1[j];
#pragma unroll
    for (int bb = 0; bb < 32; bb += 4) {
        float wv[4];
#pragma unroll
        for (int u = 0; u < 4; u++) wv[u] = w1[(bb + u) * 128 + j];
#pragma unroll
        for (int i = 0; i < 16; i++) {
            float4 m4 = *(const float4*)&mi[(nh * 16 + i) * 32 + bb];
            h[i] = fmaf(m4.x, wv[0], h[i]);
            h[i] = fmaf(m4.y, wv[1], h[i]);
            h[i] = fmaf(m4.z, wv[2], h[i]);
            h[i] = fmaf(m4.w, wv[3], h[i]);
        }
    }
#pragma unroll
    for (int i = 0; i < 16; i++) sh[(nh * 16 + i) * 128 + j] = silu_f(h[i]);
    __syncthreads();

    float acc[16];
#pragma unroll
    for (int i = 0; i < 16; i++) acc[i] = b2[j];
    for (int hb = 0; hb < 128; hb += 4) {
        float wv[4];
#pragma unroll
        for (int u = 0; u < 4; u++) wv[u] = w2[(hb + u) * 128 + j];
#pragma unroll
        for (int i = 0; i < 16; i++) {
            float4 s4 = *(const float4*)&sh[(nh * 16 + i) * 128 + hb];
            acc[i] = fmaf(s4.x, wv[0], acc[i]);
            acc[i] = fmaf(s4.y, wv[1], acc[i]);
            acc[i] = fmaf(s4.z, wv[2], acc[i]);
            acc[i] = fmaf(s4.w, wv[3], acc[i]);
        }
    }
#pragma unroll
    for (int i = 0; i < 16; i++) {
        int n = n0 + nh * 16 + i;
        if (n < N_NODES) out[(size_t)n * 128 + j] = acc[i];
    }
}

// ---------------- K2: filt (thread per edge) ----------------
__global__ __launch_bounds__(256) void k_filt(const float* __restrict__ dis_vec,
                                              const float* __restrict__ fw1,
                                              const float* __restrict__ fw2,
                                              const float* __restrict__ fb2,
                                              float* __restrict__ out) {
    int e = blockIdx.x * 256 + threadIdx.x;
    if (e >= N_EDGES) return;
    float dx = dis_vec[3 * e], dy = dis_vec[3 * e + 1], dz = dis_vec[3 * e + 2];
    float ax = dx + 1e-9f, ay = dy + 1e-9f, az = dz + 1e-9f;
    float dis = sqrtf(ax * ax + ay * ay + az * az);
    float x = dx + 1e-8f, y = dy + 1e-8f, z = dz + 1e-8f;
    // prefactor * PREF2, t order: (0,0,2),(0,1,1),(0,2,0),(1,0,1),(1,1,0),(2,0,0)
    float pre[6];
    pre[0] = z * z;      pre[1] = y * z * R2; pre[2] = y * y;
    pre[3] = x * z * R2; pre[4] = x * y * R2; pre[5] = x * x;
    float A = 0.f, B = 0.f;
#pragma unroll
    for (int t = 0; t < 6; t++) { A = fmaf(pre[t], pre[t], A); B += pre[t]; }
    float q[6];
#pragma unroll
    for (int tp = 0; tp < 6; tp++) {
        float s = 0.f;
#pragma unroll
        for (int t = 0; t < 6; t++) s = fmaf(pre[t], fw1[t * 6 + tp], s);
        q[tp] = s;
    }
    float bias = fb2[0];
    float w2r[6];
#pragma unroll
    for (int t = 0; t < 6; t++) w2r[t] = fw2[t];
    float* orow = out + (size_t)e * 32;
    for (int b4 = 0; b4 < 32; b4 += 4) {
        float ob[4];
#pragma unroll
        for (int u = 0; u < 4; u++) {
            int b = b4 + u;
            float offb = (float)((double)b * STEP_D);
            float dd = dis - offb;
            float g = __expf(COEFF * dd * dd);
            // ||gauss + 1e-8||^2 over t, expanded: g^2*A + 2e-8*g*B + 6e-16
            float ns = fmaf(g * g, A, fmaf(2e-8f * g, B, 6e-16f));
            float rn = 1.0f / (sqrtf(ns) + 1.0f);
            float s = g * rn;
            float o = bias;
#pragma unroll
            for (int tp = 0; tp < 6; tp++) o = fmaf(silu_f(s * q[tp]), w2r[tp], o);
            ob[u] = o;
        }
        ((float4*)orow)[b4 >> 2] = make_float4(ob[0], ob[1], ob[2], ob[3]);
    }
}

extern "C" void kernel_launch(void* const* d_in, const int* in_sizes, int n_in,
                              void* d_out, int out_size, void* d_ws, size_t ws_size,
                              hipStream_t stream) {
    (void)in_sizes; (void)n_in; (void)out_size; (void)ws_size;
    const float* feat    = (const float*)d_in[0];
    const float* dis_vec = (const float*)d_in[1];
    const float* cj_w1   = (const float*)d_in[2];
    const float* cj_b1   = (const float*)d_in[3];
    const float* cj_w2   = (const float*)d_in[4];
    const float* cj_b2   = (const float*)d_in[5];
    const float* msg_w1  = (const float*)d_in[6];
    const float* msg_b1  = (const float*)d_in[7];
    const float* msg_w2  = (const float*)d_in[8];
    const float* msg_b2  = (const float*)d_in[9];
    const float* filt_w1 = (const float*)d_in[10];
    const float* filt_w2 = (const float*)d_in[11];
    const float* filt_b2 = (const float*)d_in[12];
    const int*   src     = (const int*)d_in[13];
    const int*   dst     = (const int*)d_in[14];
    float* out = (float*)d_out;

    // workspace layout (elements), all 16B aligned
    float* ws     = (float*)d_ws;
    float* cj     = ws;                    // 50048
    float* msg_in = cj + 50048;            // 1600000 (+slack)
    int*   cnt    = (int*)(msg_in + 1600256);  // 50048
    int*   offs   = cnt + 50048;           // 50048
    int*   cursor = offs + 50048;          // 50048
    int*   bsum   = cursor + 50048;        // 64
    int*   bbase  = bsum + 64;             // 64
    int*   elist  = bbase + 64;            // 800000
    // total ~10.5 MB

    hipMemsetAsync(cnt, 0, N_NODES * sizeof(int), stream);

    k_cj<<<(N_NODES + 31) / 32, 256, 0, stream>>>(feat, cj_w1, cj_b1, cj_w2, cj_b2, cj);
    k_count<<<(N_EDGES + 255) / 256, 256, 0, stream>>>(src, cnt);
    k_scan1<<<49, 1024, 0, stream>>>(cnt, offs, bsum);
    k_scan2<<<1, 64, 0, stream>>>(bsum, bbase, 49);
    k_scan3<<<49, 1024, 0, stream>>>(offs, bbase, cursor);
    k_scatter<<<(N_EDGES + 255) / 256, 256, 0, stream>>>(src, cursor, elist);
    k_agg<<<N_NODES / 4, 256, 0, stream>>>(dis_vec, dst, elist, offs, cnt, cj, msg_in);
    k_msg<<<(N_NODES + 31) / 32, 256, 0, stream>>>(msg_in, msg_w1, msg_b1, msg_w2, msg_b2, out);
    k_filt<<<(N_EDGES + 255) / 256, 256, 0, stream>>>(dis_vec, filt_w1, filt_w2, filt_b2,
                                                      out + (size_t)N_NODES * NA);
}

// Round 3
// 483.343 us; speedup vs baseline: 2.0021x; 1.1623x over previous
//
#include <hip/hip_runtime.h>
#include <math.h>

#define N_NODES 50000
#define N_EDGES 800000
#define NB 32
#define NA 128

constexpr double STEP_D = 10.0 / 31.0;
constexpr float  STEP_F = (float)(10.0 / 31.0);       // matches np.float32 width
constexpr float  COEFF  = -0.5f / (STEP_F * STEP_F);  // -0.5/width^2
constexpr float  R2     = 1.41421356237309515f;       // sqrt(2) = PREF2 for mixed terms

__device__ __forceinline__ float silu_f(float x) {
    return x / (1.0f + __expf(-x));
}

// ---------------- K1: cj = MLP(feat) -> [N] scalar ----------------
// Tiled: block=256 (4 waves), 32 nodes/block, thread = output column j for 16 nodes.
__global__ __launch_bounds__(256) void k_cj(const float* __restrict__ feat,
                                            const float* __restrict__ w1,   // [128,128] orig
                                            const float* __restrict__ b1,
                                            const float* __restrict__ w2,   // [128,1]
                                            const float* __restrict__ b2,
                                            float* __restrict__ cj) {
    __shared__ float fls[32 * 128];   // 16 KB feat tile
    __shared__ float red[2][32];
    int tid  = threadIdx.x;
    int lane = tid & 63;
    int wave = tid >> 6;         // 0..3
    int jh   = wave & 1;         // j half
    int nh   = wave >> 1;        // node half
    int j    = jh * 64 + lane;   // 0..127
    int n0   = blockIdx.x * 32;

    // stage feat tile (coalesced float4, clamped for tail block)
    {
        const float4* fp = (const float4*)feat;
        int base = n0 * 32;                    // float4 index
        int maxi = N_NODES * 32 - 1;
#pragma unroll
        for (int r = 0; r < 4; r++) {
            int idx = base + r * 256 + tid;
            ((float4*)fls)[r * 256 + tid] = fp[min(idx, maxi)];
        }
    }
    __syncthreads();

    float h[16];
#pragma unroll
    for (int i = 0; i < 16; i++) h[i] = b1[j];
    for (int kb = 0; kb < 128; kb += 4) {
        float wv[4];
#pragma unroll
        for (int u = 0; u < 4; u++) wv[u] = w1[(kb + u) * 128 + j];
#pragma unroll
        for (int i = 0; i < 16; i++) {
            float4 f4 = *(const float4*)&fls[(nh * 16 + i) * 128 + kb];
            h[i] = fmaf(f4.x, wv[0], h[i]);
            h[i] = fmaf(f4.y, wv[1], h[i]);
            h[i] = fmaf(f4.z, wv[2], h[i]);
            h[i] = fmaf(f4.w, wv[3], h[i]);
        }
    }
    // epilogue: cj[n] = b2 + sum_j silu(h)*w2[j]
    float w2j = w2[j];
    float keep = 0.f;
#pragma unroll
    for (int i = 0; i < 16; i++) {
        float v = silu_f(h[i]) * w2j;
#pragma unroll
        for (int m = 1; m < 64; m <<= 1) v += __shfl_xor(v, m, 64);
        if (lane == i) keep = v;
    }
    if (lane < 16) red[jh][nh * 16 + lane] = keep;
    __syncthreads();
    if (tid < 32) {
        int n = n0 + tid;
        if (n < N_NODES) cj[n] = b2[0] + red[0][tid] + red[1][tid];
    }
}

// ---------------- K3a: count edges per src node ----------------
__global__ void k_count(const int* __restrict__ src, int* __restrict__ cnt) {
    int e = blockIdx.x * 256 + threadIdx.x;
    if (e < N_EDGES) atomicAdd(&cnt[src[e]], 1);
}

// ---------------- K3b: two-level exclusive scan ----------------
__global__ void k_scan1(const int* __restrict__ cnt, int* __restrict__ offs,
                        int* __restrict__ bsum) {
    __shared__ int s[1024];
    int i = blockIdx.x * 1024 + threadIdx.x;
    int v = (i < N_NODES) ? cnt[i] : 0;
    s[threadIdx.x] = v;
    __syncthreads();
    for (int o = 1; o < 1024; o <<= 1) {
        int t = (threadIdx.x >= (unsigned)o) ? s[threadIdx.x - o] : 0;
        __syncthreads();
        s[threadIdx.x] += t;
        __syncthreads();
    }
    if (i < N_NODES) offs[i] = s[threadIdx.x] - v;  // exclusive within block
    if (threadIdx.x == 1023) bsum[blockIdx.x] = s[1023];
}

__global__ void k_scan2(const int* __restrict__ bsum, int* __restrict__ bbase, int nb) {
    if (threadIdx.x == 0) {
        int r = 0;
        for (int i = 0; i < nb; i++) { bbase[i] = r; r += bsum[i]; }
    }
}

__global__ void k_scan3(int* __restrict__ offs, const int* __restrict__ bbase,
                        int* __restrict__ cursor) {
    int i = blockIdx.x * 1024 + threadIdx.x;
    if (i < N_NODES) {
        int v = offs[i] + bbase[blockIdx.x];
        offs[i] = v;
        cursor[i] = v;
    }
}

// ---------------- K3c: scatter per-edge records into sorted-by-src buffer ----------
// record (8 floats): [dis, cj*z^2, cj*yz*R2, cj*y^2, cj*xz*R2, cj*xy*R2, cj*x^2, 0]
__global__ void k_scatter(const int* __restrict__ src, const int* __restrict__ dst,
                          const float* __restrict__ dis_vec, const float* __restrict__ cj,
                          int* __restrict__ cursor, float* __restrict__ sedge) {
    int e = blockIdx.x * 256 + threadIdx.x;
    if (e >= N_EDGES) return;
    int p = atomicAdd(&cursor[src[e]], 1);
    float dx = dis_vec[3 * e], dy = dis_vec[3 * e + 1], dz = dis_vec[3 * e + 2];
    float cjd = cj[dst[e]];
    float ax = dx + 1e-9f, ay = dy + 1e-9f, az = dz + 1e-9f;
    float dis = sqrtf(ax * ax + ay * ay + az * az);
    float x = dx + 1e-8f, y = dy + 1e-8f, z = dz + 1e-8f;
    float4* op = (float4*)(sedge + (size_t)p * 8);
    op[0] = make_float4(dis, z * z * cjd, y * z * R2 * cjd, y * y * cjd);
    op[1] = make_float4(x * z * R2 * cjd, x * y * R2 * cjd, x * x * cjd, 0.f);
}

// ---------------- K4: per-node aggregation (wave per node), streams sedge --------
// lane: b = lane>>1 (basis), th = lane&1 selects t-triple {0,1,2} or {3,4,5}
__global__ __launch_bounds__(256) void k_agg(const float* __restrict__ sedge,
                                             const int* __restrict__ offs,
                                             const int* __restrict__ cnt,
                                             float* __restrict__ msg_in) {
    int lane = threadIdx.x & 63;
    int n = blockIdx.x * 4 + (threadIdx.x >> 6);
    if (n >= N_NODES) return;
    int b = lane >> 1, th = lane & 1;
    float offb = (float)((double)b * STEP_D);
    int beg = offs[n];
    int deg = cnt[n];
    const float4* sp = (const float4*)sedge + (size_t)beg * 2;
    float a0 = 0.f, a1 = 0.f, a2 = 0.f;
    int i = 0;
    for (; i + 2 <= deg; i += 2) {
        float4 r0 = sp[0], r1 = sp[1], r2 = sp[2], r3 = sp[3];
        sp += 4;
        float dd0 = r0.x - offb;
        float dd1 = r2.x - offb;
        float g0 = __expf(COEFF * dd0 * dd0);
        float g1 = __expf(COEFF * dd1 * dd1);
        float w00 = th ? r1.x : r0.y, w01 = th ? r1.y : r0.z, w02 = th ? r1.z : r0.w;
        float w10 = th ? r3.x : r2.y, w11 = th ? r3.y : r2.z, w12 = th ? r3.z : r2.w;
        a0 = fmaf(g0, w00, a0);
        a1 = fmaf(g0, w01, a1);
        a2 = fmaf(g0, w02, a2);
        a0 = fmaf(g1, w10, a0);
        a1 = fmaf(g1, w11, a1);
        a2 = fmaf(g1, w12, a2);
    }
    if (i < deg) {
        float4 r0 = sp[0], r1 = sp[1];
        float dd0 = r0.x - offb;
        float g0 = __expf(COEFF * dd0 * dd0);
        float w00 = th ? r1.x : r0.y, w01 = th ? r1.y : r0.z, w02 = th ? r1.z : r0.w;
        a0 = fmaf(g0, w00, a0);
        a1 = fmaf(g0, w01, a1);
        a2 = fmaf(g0, w02, a2);
    }
    float s = a0 * a0 + a1 * a1 + a2 * a2;
    float f2 = s + __shfl_xor(s, 1, 64);  // sum over all 6 t
    float p = f2 + 1e-9f;
    p = p * p;
    float tot = p;
#pragma unroll
    for (int m = 1; m < 64; m <<= 1) tot += __shfl_xor(tot, m, 64);
    // each b counted twice (both th lanes) -> halve
    float nrm = sqrtf(0.5f * tot);
    float val = f2 / (nrm + 1.0f);
    if (th == 0) msg_in[(size_t)n * NB + b] = val;
}

// ---------------- K5: msg MLP, tiled (32 nodes/block, 256 threads) ----------------
__global__ __launch_bounds__(256) void k_msg(const float* __restrict__ msg_in,
                                             const float* __restrict__ w1,   // [32,128] orig
                                             const float* __restrict__ b1,
                                             const float* __restrict__ w2,   // [128,128] orig
                                             const float* __restrict__ b2,
                                             float* __restrict__ out) {
    __shared__ float mi[32 * 32];     // 4 KB input tile
    __shared__ float sh[32 * 128];    // 16 KB hidden tile
    int tid  = threadIdx.x;
    int lane = tid & 63;
    int wave = tid >> 6;
    int jh   = wave & 1;
    int nh   = wave >> 1;
    int j    = jh * 64 + lane;
    int n0   = blockIdx.x * 32;

    // stage msg_in tile (32 nodes x 32 basis = 1024 floats)
    {
        const float4* srcp = (const float4*)msg_in;
        int idx = n0 * 8 + tid;                  // float4 index
        int maxi = N_NODES * 8 - 1;
        ((float4*)mi)[tid] = srcp[min(idx, maxi)];
    }
    __syncthreads();

    float h[16];
#pragma unroll
    for (int i = 0; i < 16; i++) h[i] = b1[j];
#pragma unroll
    for (int bb = 0; bb < 32; bb += 4) {
        float wv[4];
#pragma unroll
        for (int u = 0; u < 4; u++) wv[u] = w1[(bb + u) * 128 + j];
#pragma unroll
        for (int i = 0; i < 16; i++) {
            float4 m4 = *(const float4*)&mi[(nh * 16 + i) * 32 + bb];
            h[i] = fmaf(m4.x, wv[0], h[i]);
            h[i] = fmaf(m4.y, wv[1], h[i]);
            h[i] = fmaf(m4.z, wv[2], h[i]);
            h[i] = fmaf(m4.w, wv[3], h[i]);
        }
    }
#pragma unroll
    for (int i = 0; i < 16; i++) sh[(nh * 16 + i) * 128 + j] = silu_f(h[i]);
    __syncthreads();

    float acc[16];
#pragma unroll
    for (int i = 0; i < 16; i++) acc[i] = b2[j];
    for (int hb = 0; hb < 128; hb += 4) {
        float wv[4];
#pragma unroll
        for (int u = 0; u < 4; u++) wv[u] = w2[(hb + u) * 128 + j];
#pragma unroll
        for (int i = 0; i < 16; i++) {
            float4 s4 = *(const float4*)&sh[(nh * 16 + i) * 128 + hb];
            acc[i] = fmaf(s4.x, wv[0], acc[i]);
            acc[i] = fmaf(s4.y, wv[1], acc[i]);
            acc[i] = fmaf(s4.z, wv[2], acc[i]);
            acc[i] = fmaf(s4.w, wv[3], acc[i]);
        }
    }
#pragma unroll
    for (int i = 0; i < 16; i++) {
        int n = n0 + nh * 16 + i;
        if (n < N_NODES) out[(size_t)n * 128 + j] = acc[i];
    }
}

// ---------------- K2: filt (thread per edge) ----------------
__global__ __launch_bounds__(256) void k_filt(const float* __restrict__ dis_vec,
                                              const float* __restrict__ fw1,
                                              const float* __restrict__ fw2,
                                              const float* __restrict__ fb2,
                                              float* __restrict__ out) {
    int e = blockIdx.x * 256 + threadIdx.x;
    if (e >= N_EDGES) return;
    float dx = dis_vec[3 * e], dy = dis_vec[3 * e + 1], dz = dis_vec[3 * e + 2];
    float ax = dx + 1e-9f, ay = dy + 1e-9f, az = dz + 1e-9f;
    float dis = sqrtf(ax * ax + ay * ay + az * az);
    float x = dx + 1e-8f, y = dy + 1e-8f, z = dz + 1e-8f;
    // prefactor * PREF2, t order: (0,0,2),(0,1,1),(0,2,0),(1,0,1),(1,1,0),(2,0,0)
    float pre[6];
    pre[0] = z * z;      pre[1] = y * z * R2; pre[2] = y * y;
    pre[3] = x * z * R2; pre[4] = x * y * R2; pre[5] = x * x;
    float A = 0.f, B = 0.f;
#pragma unroll
    for (int t = 0; t < 6; t++) { A = fmaf(pre[t], pre[t], A); B += pre[t]; }
    float q[6];
#pragma unroll
    for (int tp = 0; tp < 6; tp++) {
        float s = 0.f;
#pragma unroll
        for (int t = 0; t < 6; t++) s = fmaf(pre[t], fw1[t * 6 + tp], s);
        q[tp] = s;
    }
    float bias = fb2[0];
    float w2r[6];
#pragma unroll
    for (int t = 0; t < 6; t++) w2r[t] = fw2[t];
    float* orow = out + (size_t)e * 32;
    for (int b4 = 0; b4 < 32; b4 += 4) {
        float ob[4];
#pragma unroll
        for (int u = 0; u < 4; u++) {
            int b = b4 + u;
            float offb = (float)((double)b * STEP_D);
            float dd = dis - offb;
            float g = __expf(COEFF * dd * dd);
            // ||gauss + 1e-8||^2 over t, expanded: g^2*A + 2e-8*g*B + 6e-16
            float ns = fmaf(g * g, A, fmaf(2e-8f * g, B, 6e-16f));
            float rn = 1.0f / (sqrtf(ns) + 1.0f);
            float s = g * rn;
            float o = bias;
#pragma unroll
            for (int tp = 0; tp < 6; tp++) o = fmaf(silu_f(s * q[tp]), w2r[tp], o);
            ob[u] = o;
        }
        ((float4*)orow)[b4 >> 2] = make_float4(ob[0], ob[1], ob[2], ob[3]);
    }
}

extern "C" void kernel_launch(void* const* d_in, const int* in_sizes, int n_in,
                              void* d_out, int out_size, void* d_ws, size_t ws_size,
                              hipStream_t stream) {
    (void)in_sizes; (void)n_in; (void)out_size; (void)ws_size;
    const float* feat    = (const float*)d_in[0];
    const float* dis_vec = (const float*)d_in[1];
    const float* cj_w1   = (const float*)d_in[2];
    const float* cj_b1   = (const float*)d_in[3];
    const float* cj_w2   = (const float*)d_in[4];
    const float* cj_b2   = (const float*)d_in[5];
    const float* msg_w1  = (const float*)d_in[6];
    const float* msg_b1  = (const float*)d_in[7];
    const float* msg_w2  = (const float*)d_in[8];
    const float* msg_b2  = (const float*)d_in[9];
    const float* filt_w1 = (const float*)d_in[10];
    const float* filt_w2 = (const float*)d_in[11];
    const float* filt_b2 = (const float*)d_in[12];
    const int*   src     = (const int*)d_in[13];
    const int*   dst     = (const int*)d_in[14];
    float* out = (float*)d_out;

    // workspace layout (elements), all 16B aligned
    float* ws     = (float*)d_ws;
    float* cj     = ws;                        // 50048
    float* msg_in = cj + 50048;                // 1600256
    int*   cnt    = (int*)(msg_in + 1600256);  // 50048
    int*   offs   = cnt + 50048;               // 50048
    int*   cursor = offs + 50048;              // 50048
    int*   bsum   = cursor + 50048;            // 64
    int*   bbase  = bsum + 64;                 // 64
    float* sedge  = (float*)(bbase + 64);      // 6400000 (25.6 MB)
    // total ~33 MB

    hipMemsetAsync(cnt, 0, N_NODES * sizeof(int), stream);

    k_cj<<<(N_NODES + 31) / 32, 256, 0, stream>>>(feat, cj_w1, cj_b1, cj_w2, cj_b2, cj);
    k_count<<<(N_EDGES + 255) / 256, 256, 0, stream>>>(src, cnt);
    k_scan1<<<49, 1024, 0, stream>>>(cnt, offs, bsum);
    k_scan2<<<1, 64, 0, stream>>>(bsum, bbase, 49);
    k_scan3<<<49, 1024, 0, stream>>>(offs, bbase, cursor);
    k_scatter<<<(N_EDGES + 255) / 256, 256, 0, stream>>>(src, dst, dis_vec, cj, cursor, sedge);
    k_agg<<<(N_NODES + 3) / 4, 256, 0, stream>>>(sedge, offs, cnt, msg_in);
    k_msg<<<(N_NODES + 31) / 32, 256, 0, stream>>>(msg_in, msg_w1, msg_b1, msg_w2, msg_b2, out);
    k_filt<<<(N_EDGES + 255) / 256, 256, 0, stream>>>(dis_vec, filt_w1, filt_w2, filt_b2,
                                                      out + (size_t)N_NODES * NA);
}

// Round 4
// 432.152 us; speedup vs baseline: 2.2392x; 1.1185x over previous
//
#include <hip/hip_runtime.h>
#include <math.h>

#define N_NODES 50000
#define N_EDGES 800000
#define NB 32
#define NA 128

constexpr double STEP_D = 10.0 / 31.0;
constexpr float  STEP_F = (float)(10.0 / 31.0);       // matches np.float32 width
constexpr float  COEFF  = -0.5f / (STEP_F * STEP_F);  // -0.5/width^2
constexpr float  R2     = 1.41421356237309515f;       // sqrt(2) = PREF2 for mixed terms
constexpr float  INV_STEP = 3.1f;                     // 31/10
constexpr float  HWIN   = 2.05f;                      // g(HWIN) ~ 1.7e-9; 2H/step=12.7 <= 13

__device__ __forceinline__ float fast_rcp(float x) {
    return __builtin_amdgcn_rcpf(x);   // v_rcp_f32, ~1ulp
}

__device__ __forceinline__ float silu_f(float x) {
    return x * fast_rcp(1.0f + __expf(-x));
}

// ---------------- K1: cj = MLP(feat) -> [N] scalar ----------------
// Tiled: block=256 (4 waves), 32 nodes/block, thread = output column j for 16 nodes.
__global__ __launch_bounds__(256) void k_cj(const float* __restrict__ feat,
                                            const float* __restrict__ w1,   // [128,128] orig
                                            const float* __restrict__ b1,
                                            const float* __restrict__ w2,   // [128,1]
                                            const float* __restrict__ b2,
                                            float* __restrict__ cj) {
    __shared__ float fls[32 * 128];   // 16 KB feat tile
    __shared__ float red[2][32];
    int tid  = threadIdx.x;
    int lane = tid & 63;
    int wave = tid >> 6;         // 0..3
    int jh   = wave & 1;         // j half
    int nh   = wave >> 1;        // node half
    int j    = jh * 64 + lane;   // 0..127
    int n0   = blockIdx.x * 32;

    // stage feat tile (coalesced float4, clamped for tail block)
    {
        const float4* fp = (const float4*)feat;
        int base = n0 * 32;                    // float4 index
        int maxi = N_NODES * 32 - 1;
#pragma unroll
        for (int r = 0; r < 4; r++) {
            int idx = base + r * 256 + tid;
            ((float4*)fls)[r * 256 + tid] = fp[min(idx, maxi)];
        }
    }
    __syncthreads();

    float h[16];
#pragma unroll
    for (int i = 0; i < 16; i++) h[i] = b1[j];
    for (int kb = 0; kb < 128; kb += 4) {
        float wv[4];
#pragma unroll
        for (int u = 0; u < 4; u++) wv[u] = w1[(kb + u) * 128 + j];
#pragma unroll
        for (int i = 0; i < 16; i++) {
            float4 f4 = *(const float4*)&fls[(nh * 16 + i) * 128 + kb];
            h[i] = fmaf(f4.x, wv[0], h[i]);
            h[i] = fmaf(f4.y, wv[1], h[i]);
            h[i] = fmaf(f4.z, wv[2], h[i]);
            h[i] = fmaf(f4.w, wv[3], h[i]);
        }
    }
    // epilogue: cj[n] = b2 + sum_j silu(h)*w2[j]
    float w2j = w2[j];
    float keep = 0.f;
#pragma unroll
    for (int i = 0; i < 16; i++) {
        float v = silu_f(h[i]) * w2j;
#pragma unroll
        for (int m = 1; m < 64; m <<= 1) v += __shfl_xor(v, m, 64);
        if (lane == i) keep = v;
    }
    if (lane < 16) red[jh][nh * 16 + lane] = keep;
    __syncthreads();
    if (tid < 32) {
        int n = n0 + tid;
        if (n < N_NODES) cj[n] = b2[0] + red[0][tid] + red[1][tid];
    }
}

// ---------------- K3a: count edges per src node ----------------
__global__ void k_count(const int* __restrict__ src, int* __restrict__ cnt) {
    int e = blockIdx.x * 256 + threadIdx.x;
    if (e < N_EDGES) atomicAdd(&cnt[src[e]], 1);
}

// ---------------- K3b: two-level exclusive scan ----------------
__global__ void k_scan1(const int* __restrict__ cnt, int* __restrict__ offs,
                        int* __restrict__ bsum) {
    __shared__ int s[1024];
    int i = blockIdx.x * 1024 + threadIdx.x;
    int v = (i < N_NODES) ? cnt[i] : 0;
    s[threadIdx.x] = v;
    __syncthreads();
    for (int o = 1; o < 1024; o <<= 1) {
        int t = (threadIdx.x >= (unsigned)o) ? s[threadIdx.x - o] : 0;
        __syncthreads();
        s[threadIdx.x] += t;
        __syncthreads();
    }
    if (i < N_NODES) offs[i] = s[threadIdx.x] - v;  // exclusive within block
    if (threadIdx.x == 1023) bsum[blockIdx.x] = s[1023];
}

__global__ void k_scan2(const int* __restrict__ bsum, int* __restrict__ bbase, int nb) {
    if (threadIdx.x == 0) {
        int r = 0;
        for (int i = 0; i < nb; i++) { bbase[i] = r; r += bsum[i]; }
    }
}

__global__ void k_scan3(int* __restrict__ offs, const int* __restrict__ bbase,
                        int* __restrict__ cursor) {
    int i = blockIdx.x * 1024 + threadIdx.x;
    if (i < N_NODES) {
        int v = offs[i] + bbase[blockIdx.x];
        offs[i] = v;
        cursor[i] = v;
    }
}

// ---------------- K3c: scatter per-edge records into sorted-by-src buffer ----------
// record (8 floats): [dis, cj*z^2, cj*yz*R2, cj*y^2, cj*xz*R2, cj*xy*R2, cj*x^2, 0]
__global__ void k_scatter(const int* __restrict__ src, const int* __restrict__ dst,
                          const float* __restrict__ dis_vec, const float* __restrict__ cj,
                          int* __restrict__ cursor, float* __restrict__ sedge) {
    int e = blockIdx.x * 256 + threadIdx.x;
    if (e >= N_EDGES) return;
    int p = atomicAdd(&cursor[src[e]], 1);
    float dx = dis_vec[3 * e], dy = dis_vec[3 * e + 1], dz = dis_vec[3 * e + 2];
    float cjd = cj[dst[e]];
    float ax = dx + 1e-9f, ay = dy + 1e-9f, az = dz + 1e-9f;
    float dis = sqrtf(ax * ax + ay * ay + az * az);
    float x = dx + 1e-8f, y = dy + 1e-8f, z = dz + 1e-8f;
    float4* op = (float4*)(sedge + (size_t)p * 8);
    op[0] = make_float4(dis, z * z * cjd, y * z * R2 * cjd, y * y * cjd);
    op[1] = make_float4(x * z * R2 * cjd, x * y * R2 * cjd, x * x * cjd, 0.f);
}

// ---------------- K4: per-node aggregation (wave per node), streams sedge --------
// lane: b = lane>>1 (basis), th = lane&1 selects t-triple {0,1,2} or {3,4,5}
__global__ __launch_bounds__(256) void k_agg(const float* __restrict__ sedge,
                                             const int* __restrict__ offs,
                                             const int* __restrict__ cnt,
                                             float* __restrict__ msg_in) {
    int lane = threadIdx.x & 63;
    int n = blockIdx.x * 4 + (threadIdx.x >> 6);
    if (n >= N_NODES) return;
    int b = lane >> 1, th = lane & 1;
    float offb = (float)((double)b * STEP_D);
    int beg = offs[n];
    int deg = cnt[n];
    const float4* sp = (const float4*)sedge + (size_t)beg * 2;
    float a0 = 0.f, a1 = 0.f, a2 = 0.f;
    int i = 0;
    for (; i + 2 <= deg; i += 2) {
        float4 r0 = sp[0], r1 = sp[1], r2 = sp[2], r3 = sp[3];
        sp += 4;
        float dd0 = r0.x - offb;
        float dd1 = r2.x - offb;
        float g0 = __expf(COEFF * dd0 * dd0);
        float g1 = __expf(COEFF * dd1 * dd1);
        float w00 = th ? r1.x : r0.y, w01 = th ? r1.y : r0.z, w02 = th ? r1.z : r0.w;
        float w10 = th ? r3.x : r2.y, w11 = th ? r3.y : r2.z, w12 = th ? r3.z : r2.w;
        a0 = fmaf(g0, w00, a0);
        a1 = fmaf(g0, w01, a1);
        a2 = fmaf(g0, w02, a2);
        a0 = fmaf(g1, w10, a0);
        a1 = fmaf(g1, w11, a1);
        a2 = fmaf(g1, w12, a2);
    }
    if (i < deg) {
        float4 r0 = sp[0], r1 = sp[1];
        float dd0 = r0.x - offb;
        float g0 = __expf(COEFF * dd0 * dd0);
        float w00 = th ? r1.x : r0.y, w01 = th ? r1.y : r0.z, w02 = th ? r1.z : r0.w;
        a0 = fmaf(g0, w00, a0);
        a1 = fmaf(g0, w01, a1);
        a2 = fmaf(g0, w02, a2);
    }
    float s = a0 * a0 + a1 * a1 + a2 * a2;
    float f2 = s + __shfl_xor(s, 1, 64);  // sum over all 6 t
    float p = f2 + 1e-9f;
    p = p * p;
    float tot = p;
#pragma unroll
    for (int m = 1; m < 64; m <<= 1) tot += __shfl_xor(tot, m, 64);
    // each b counted twice (both th lanes) -> halve
    float nrm = sqrtf(0.5f * tot);
    float val = f2 * fast_rcp(nrm + 1.0f);
    if (th == 0) msg_in[(size_t)n * NB + b] = val;
}

// ---------------- K5: msg MLP, tiled (32 nodes/block, 256 threads) ----------------
__global__ __launch_bounds__(256) void k_msg(const float* __restrict__ msg_in,
                                             const float* __restrict__ w1,   // [32,128] orig
                                             const float* __restrict__ b1,
                                             const float* __restrict__ w2,   // [128,128] orig
                                             const float* __restrict__ b2,
                                             float* __restrict__ out) {
    __shared__ float mi[32 * 32];     // 4 KB input tile
    __shared__ float sh[32 * 128];    // 16 KB hidden tile
    int tid  = threadIdx.x;
    int lane = tid & 63;
    int wave = tid >> 6;
    int jh   = wave & 1;
    int nh   = wave >> 1;
    int j    = jh * 64 + lane;
    int n0   = blockIdx.x * 32;

    // stage msg_in tile (32 nodes x 32 basis = 1024 floats)
    {
        const float4* srcp = (const float4*)msg_in;
        int idx = n0 * 8 + tid;                  // float4 index
        int maxi = N_NODES * 8 - 1;
        ((float4*)mi)[tid] = srcp[min(idx, maxi)];
    }
    __syncthreads();

    float h[16];
#pragma unroll
    for (int i = 0; i < 16; i++) h[i] = b1[j];
#pragma unroll
    for (int bb = 0; bb < 32; bb += 4) {
        float wv[4];
#pragma unroll
        for (int u = 0; u < 4; u++) wv[u] = w1[(bb + u) * 128 + j];
#pragma unroll
        for (int i = 0; i < 16; i++) {
            float4 m4 = *(const float4*)&mi[(nh * 16 + i) * 32 + bb];
            h[i] = fmaf(m4.x, wv[0], h[i]);
            h[i] = fmaf(m4.y, wv[1], h[i]);
            h[i] = fmaf(m4.z, wv[2], h[i]);
            h[i] = fmaf(m4.w, wv[3], h[i]);
        }
    }
#pragma unroll
    for (int i = 0; i < 16; i++) sh[(nh * 16 + i) * 128 + j] = silu_f(h[i]);
    __syncthreads();

    float acc[16];
#pragma unroll
    for (int i = 0; i < 16; i++) acc[i] = b2[j];
    for (int hb = 0; hb < 128; hb += 4) {
        float wv[4];
#pragma unroll
        for (int u = 0; u < 4; u++) wv[u] = w2[(hb + u) * 128 + j];
#pragma unroll
        for (int i = 0; i < 16; i++) {
            float4 s4 = *(const float4*)&sh[(nh * 16 + i) * 128 + hb];
            acc[i] = fmaf(s4.x, wv[0], acc[i]);
            acc[i] = fmaf(s4.y, wv[1], acc[i]);
            acc[i] = fmaf(s4.z, wv[2], acc[i]);
            acc[i] = fmaf(s4.w, wv[3], acc[i]);
        }
    }
#pragma unroll
    for (int i = 0; i < 16; i++) {
        int n = n0 + nh * 16 + i;
        if (n < N_NODES) out[(size_t)n * 128 + j] = acc[i];
    }
}

// ---------------- K2: filt (thread per edge, windowed gaussian) ----------------
// Outside |dis - offb| <= 2.05, g < 1.7e-9 -> filt == bias to ~1e-8 (threshold 1.2e-3).
// Row buffer lives in LDS (stride 36 words: 16B-aligned, conflict-free banks).
__global__ __launch_bounds__(256) void k_filt(const float* __restrict__ dis_vec,
                                              const float* __restrict__ fw1,
                                              const float* __restrict__ fw2,
                                              const float* __restrict__ fb2,
                                              float* __restrict__ out) {
    __shared__ float buf[256 * 36];   // 36 KB
    int tid = threadIdx.x;
    int e = blockIdx.x * 256 + tid;
    if (e >= N_EDGES) return;
    float dx = dis_vec[3 * e], dy = dis_vec[3 * e + 1], dz = dis_vec[3 * e + 2];
    float ax = dx + 1e-9f, ay = dy + 1e-9f, az = dz + 1e-9f;
    float dis = sqrtf(ax * ax + ay * ay + az * az);
    float x = dx + 1e-8f, y = dy + 1e-8f, z = dz + 1e-8f;
    // prefactor * PREF2, t order: (0,0,2),(0,1,1),(0,2,0),(1,0,1),(1,1,0),(2,0,0)
    float pre[6];
    pre[0] = z * z;      pre[1] = y * z * R2; pre[2] = y * y;
    pre[3] = x * z * R2; pre[4] = x * y * R2; pre[5] = x * x;
    float A = 0.f, B = 0.f;
#pragma unroll
    for (int t = 0; t < 6; t++) { A = fmaf(pre[t], pre[t], A); B += pre[t]; }
    float q[6];
#pragma unroll
    for (int tp = 0; tp < 6; tp++) {
        float s = 0.f;
#pragma unroll
        for (int t = 0; t < 6; t++) s = fmaf(pre[t], fw1[t * 6 + tp], s);
        q[tp] = s;
    }
    float bias = fb2[0];
    float w2r[6];
#pragma unroll
    for (int t = 0; t < 6; t++) w2r[t] = fw2[t];

    // init row to bias
    float* row = &buf[tid * 36];
    float4 b4v = make_float4(bias, bias, bias, bias);
#pragma unroll
    for (int r = 0; r < 8; r++) ((float4*)row)[r] = b4v;

    // windowed exact computation
    int b_lo = (int)ceilf((dis - HWIN) * INV_STEP);
#pragma unroll
    for (int k = 0; k < 14; k++) {
        int b = b_lo + k;
        float offb = (float)((double)b * STEP_D);
        float dd = dis - offb;
        float g = __expf(COEFF * dd * dd);
        // ||gauss + 1e-8||^2 over t, expanded: g^2*A + 2e-8*g*B + 6e-16
        float ns = fmaf(g * g, A, fmaf(2e-8f * g, B, 6e-16f));
        float rn = fast_rcp(sqrtf(ns) + 1.0f);
        float s = g * rn;
        float o = bias;
#pragma unroll
        for (int tp = 0; tp < 6; tp++) o = fmaf(silu_f(s * q[tp]), w2r[tp], o);
        if ((unsigned)b < 32u) row[b] = o;
    }

    // write back own row (coalesces through L2; full 128B line per edge)
    float4* orow = (float4*)(out + (size_t)e * 32);
#pragma unroll
    for (int r = 0; r < 8; r++) orow[r] = ((float4*)row)[r];
}

extern "C" void kernel_launch(void* const* d_in, const int* in_sizes, int n_in,
                              void* d_out, int out_size, void* d_ws, size_t ws_size,
                              hipStream_t stream) {
    (void)in_sizes; (void)n_in; (void)out_size; (void)ws_size;
    const float* feat    = (const float*)d_in[0];
    const float* dis_vec = (const float*)d_in[1];
    const float* cj_w1   = (const float*)d_in[2];
    const float* cj_b1   = (const float*)d_in[3];
    const float* cj_w2   = (const float*)d_in[4];
    const float* cj_b2   = (const float*)d_in[5];
    const float* msg_w1  = (const float*)d_in[6];
    const float* msg_b1  = (const float*)d_in[7];
    const float* msg_w2  = (const float*)d_in[8];
    const float* msg_b2  = (const float*)d_in[9];
    const float* filt_w1 = (const float*)d_in[10];
    const float* filt_w2 = (const float*)d_in[11];
    const float* filt_b2 = (const float*)d_in[12];
    const int*   src     = (const int*)d_in[13];
    const int*   dst     = (const int*)d_in[14];
    float* out = (float*)d_out;

    // workspace layout (elements), all 16B aligned
    float* ws     = (float*)d_ws;
    float* cj     = ws;                        // 50048
    float* msg_in = cj + 50048;                // 1600256
    int*   cnt    = (int*)(msg_in + 1600256);  // 50048
    int*   offs   = cnt + 50048;               // 50048
    int*   cursor = offs + 50048;              // 50048
    int*   bsum   = cursor + 50048;            // 64
    int*   bbase  = bsum + 64;                 // 64
    float* sedge  = (float*)(bbase + 64);      // 6400000 (25.6 MB)
    // total ~33 MB

    hipMemsetAsync(cnt, 0, N_NODES * sizeof(int), stream);

    k_cj<<<(N_NODES + 31) / 32, 256, 0, stream>>>(feat, cj_w1, cj_b1, cj_w2, cj_b2, cj);
    k_count<<<(N_EDGES + 255) / 256, 256, 0, stream>>>(src, cnt);
    k_scan1<<<49, 1024, 0, stream>>>(cnt, offs, bsum);
    k_scan2<<<1, 64, 0, stream>>>(bsum, bbase, 49);
    k_scan3<<<49, 1024, 0, stream>>>(offs, bbase, cursor);
    k_scatter<<<(N_EDGES + 255) / 256, 256, 0, stream>>>(src, dst, dis_vec, cj, cursor, sedge);
    k_agg<<<(N_NODES + 3) / 4, 256, 0, stream>>>(sedge, offs, cnt, msg_in);
    k_msg<<<(N_NODES + 31) / 32, 256, 0, stream>>>(msg_in, msg_w1, msg_b1, msg_w2, msg_b2, out);
    k_filt<<<(N_EDGES + 255) / 256, 256, 0, stream>>>(dis_vec, filt_w1, filt_w2, filt_b2,
                                                      out + (size_t)N_NODES * NA);
}

// Round 5
// 404.479 us; speedup vs baseline: 2.3924x; 1.0684x over previous
//
#include <hip/hip_runtime.h>
#include <math.h>

#define N_NODES 50000
#define N_EDGES 800000
#define NB 32
#define NA 128

constexpr double STEP_D = 10.0 / 31.0;
constexpr float  STEP_F = (float)(10.0 / 31.0);       // matches np.float32 width
constexpr float  COEFF  = -0.5f / (STEP_F * STEP_F);  // -0.5/width^2
constexpr float  R2     = 1.41421356237309515f;       // sqrt(2) = PREF2 for mixed terms
constexpr float  INV_STEP = 3.1f;                     // 31/10
constexpr float  HWIN   = 2.05f;                      // g(HWIN) ~ 1.7e-9; 2H/step=12.7 <= 13

__device__ __forceinline__ float fast_rcp(float x) {
    return __builtin_amdgcn_rcpf(x);   // v_rcp_f32, ~1ulp
}

__device__ __forceinline__ float silu_f(float x) {
    return x * fast_rcp(1.0f + __expf(-x));
}

// ---------------- K1: cj = MLP(feat) -> [N] scalar ----------------
// Block=256 (4 waves), 64 nodes/block. Thread owns 4 j-columns (j0=4*jq) x 8 nodes.
// LDS traffic: each node row read by 32 threads (not 128) -> 0.8 GB total.
__global__ __launch_bounds__(256) void k_cj(const float* __restrict__ feat,
                                            const float* __restrict__ w1,   // [128,128] orig
                                            const float* __restrict__ b1,
                                            const float* __restrict__ w2,   // [128,1]
                                            const float* __restrict__ b2,
                                            float* __restrict__ cj) {
    __shared__ float fls[64 * 128];   // 32 KB feat tile
    int tid = threadIdx.x;
    int jq  = tid & 31;          // j quad: j0 = 4*jq
    int ng  = tid >> 5;          // node group 0..7 (8 nodes each)
    int j0  = jq * 4;
    int n0  = blockIdx.x * 64;

    // stage feat tile (coalesced float4, clamped for tail block)
    {
        const float4* fp = (const float4*)feat;
        int base = n0 * 32;                    // float4 index
        int maxi = N_NODES * 32 - 1;
#pragma unroll
        for (int r = 0; r < 8; r++) {
            int idx = base + r * 256 + tid;
            ((float4*)fls)[r * 256 + tid] = fp[min(idx, maxi)];
        }
    }
    __syncthreads();

    float4 bv = *(const float4*)&b1[j0];
    float h[8][4];
#pragma unroll
    for (int i = 0; i < 8; i++) {
        h[i][0] = bv.x; h[i][1] = bv.y; h[i][2] = bv.z; h[i][3] = bv.w;
    }
    for (int kb = 0; kb < 128; kb += 4) {
        float4 wv[4];
#pragma unroll
        for (int u = 0; u < 4; u++) wv[u] = *(const float4*)&w1[(kb + u) * 128 + j0];
#pragma unroll
        for (int i = 0; i < 8; i++) {
            float4 f4 = *(const float4*)&fls[(ng * 8 + i) * 128 + kb];
            h[i][0] = fmaf(f4.x, wv[0].x, h[i][0]);
            h[i][1] = fmaf(f4.x, wv[0].y, h[i][1]);
            h[i][2] = fmaf(f4.x, wv[0].z, h[i][2]);
            h[i][3] = fmaf(f4.x, wv[0].w, h[i][3]);
            h[i][0] = fmaf(f4.y, wv[1].x, h[i][0]);
            h[i][1] = fmaf(f4.y, wv[1].y, h[i][1]);
            h[i][2] = fmaf(f4.y, wv[1].z, h[i][2]);
            h[i][3] = fmaf(f4.y, wv[1].w, h[i][3]);
            h[i][0] = fmaf(f4.z, wv[2].x, h[i][0]);
            h[i][1] = fmaf(f4.z, wv[2].y, h[i][1]);
            h[i][2] = fmaf(f4.z, wv[2].z, h[i][2]);
            h[i][3] = fmaf(f4.z, wv[2].w, h[i][3]);
            h[i][0] = fmaf(f4.w, wv[3].x, h[i][0]);
            h[i][1] = fmaf(f4.w, wv[3].y, h[i][1]);
            h[i][2] = fmaf(f4.w, wv[3].z, h[i][2]);
            h[i][3] = fmaf(f4.w, wv[3].w, h[i][3]);
        }
    }
    // epilogue: cj[n] = b2 + sum_j silu(h)*w2[j]; reduce across the 32-lane jq group
    float4 w2v = *(const float4*)&w2[j0];
    float keep = 0.f;
#pragma unroll
    for (int i = 0; i < 8; i++) {
        float v = silu_f(h[i][0]) * w2v.x + silu_f(h[i][1]) * w2v.y
                + silu_f(h[i][2]) * w2v.z + silu_f(h[i][3]) * w2v.w;
#pragma unroll
        for (int m = 1; m < 32; m <<= 1) v += __shfl_xor(v, m, 64);
        if (jq == i) keep = v;
    }
    if (jq < 8) {
        int n = n0 + ng * 8 + jq;
        if (n < N_NODES) cj[n] = b2[0] + keep;
    }
}

// ---------------- K3a: count edges per src node ----------------
__global__ void k_count(const int* __restrict__ src, int* __restrict__ cnt) {
    int e = blockIdx.x * 256 + threadIdx.x;
    if (e < N_EDGES) atomicAdd(&cnt[src[e]], 1);
}

// ---------------- K3b: two-level exclusive scan ----------------
__global__ void k_scan1(const int* __restrict__ cnt, int* __restrict__ offs,
                        int* __restrict__ bsum) {
    __shared__ int s[1024];
    int i = blockIdx.x * 1024 + threadIdx.x;
    int v = (i < N_NODES) ? cnt[i] : 0;
    s[threadIdx.x] = v;
    __syncthreads();
    for (int o = 1; o < 1024; o <<= 1) {
        int t = (threadIdx.x >= (unsigned)o) ? s[threadIdx.x - o] : 0;
        __syncthreads();
        s[threadIdx.x] += t;
        __syncthreads();
    }
    if (i < N_NODES) offs[i] = s[threadIdx.x] - v;  // exclusive within block
    if (threadIdx.x == 1023) bsum[blockIdx.x] = s[1023];
}

__global__ void k_scan2(const int* __restrict__ bsum, int* __restrict__ bbase, int nb) {
    if (threadIdx.x == 0) {
        int r = 0;
        for (int i = 0; i < nb; i++) { bbase[i] = r; r += bsum[i]; }
    }
}

__global__ void k_scan3(int* __restrict__ offs, const int* __restrict__ bbase,
                        int* __restrict__ cursor) {
    int i = blockIdx.x * 1024 + threadIdx.x;
    if (i < N_NODES) {
        int v = offs[i] + bbase[blockIdx.x];
        offs[i] = v;
        cursor[i] = v;
    }
}

// ---------------- K3c: scatter per-edge records into sorted-by-src buffer ----------
// record (8 floats): [dis, cj*z^2, cj*yz*R2, cj*y^2, cj*xz*R2, cj*xy*R2, cj*x^2, 0]
__global__ void k_scatter(const int* __restrict__ src, const int* __restrict__ dst,
                          const float* __restrict__ dis_vec, const float* __restrict__ cj,
                          int* __restrict__ cursor, float* __restrict__ sedge) {
    int e = blockIdx.x * 256 + threadIdx.x;
    if (e >= N_EDGES) return;
    int p = atomicAdd(&cursor[src[e]], 1);
    float dx = dis_vec[3 * e], dy = dis_vec[3 * e + 1], dz = dis_vec[3 * e + 2];
    float cjd = cj[dst[e]];
    float ax = dx + 1e-9f, ay = dy + 1e-9f, az = dz + 1e-9f;
    float dis = sqrtf(ax * ax + ay * ay + az * az);
    float x = dx + 1e-8f, y = dy + 1e-8f, z = dz + 1e-8f;
    float4* op = (float4*)(sedge + (size_t)p * 8);
    op[0] = make_float4(dis, z * z * cjd, y * z * R2 * cjd, y * y * cjd);
    op[1] = make_float4(x * z * R2 * cjd, x * y * R2 * cjd, x * x * cjd, 0.f);
}

// ---------------- K4: per-node aggregation (wave per node), streams sedge --------
// lane: b = lane>>1 (basis), th = lane&1 selects t-triple {0,1,2} or {3,4,5}
__global__ __launch_bounds__(256) void k_agg(const float* __restrict__ sedge,
                                             const int* __restrict__ offs,
                                             const int* __restrict__ cnt,
                                             float* __restrict__ msg_in) {
    int lane = threadIdx.x & 63;
    int n = blockIdx.x * 4 + (threadIdx.x >> 6);
    if (n >= N_NODES) return;
    int b = lane >> 1, th = lane & 1;
    float offb = (float)((double)b * STEP_D);
    int beg = offs[n];
    int deg = cnt[n];
    const float4* sp = (const float4*)sedge + (size_t)beg * 2;
    float a0 = 0.f, a1 = 0.f, a2 = 0.f;
    int i = 0;
    for (; i + 2 <= deg; i += 2) {
        float4 r0 = sp[0], r1 = sp[1], r2 = sp[2], r3 = sp[3];
        sp += 4;
        float dd0 = r0.x - offb;
        float dd1 = r2.x - offb;
        float g0 = __expf(COEFF * dd0 * dd0);
        float g1 = __expf(COEFF * dd1 * dd1);
        float w00 = th ? r1.x : r0.y, w01 = th ? r1.y : r0.z, w02 = th ? r1.z : r0.w;
        float w10 = th ? r3.x : r2.y, w11 = th ? r3.y : r2.z, w12 = th ? r3.z : r2.w;
        a0 = fmaf(g0, w00, a0);
        a1 = fmaf(g0, w01, a1);
        a2 = fmaf(g0, w02, a2);
        a0 = fmaf(g1, w10, a0);
        a1 = fmaf(g1, w11, a1);
        a2 = fmaf(g1, w12, a2);
    }
    if (i < deg) {
        float4 r0 = sp[0], r1 = sp[1];
        float dd0 = r0.x - offb;
        float g0 = __expf(COEFF * dd0 * dd0);
        float w00 = th ? r1.x : r0.y, w01 = th ? r1.y : r0.z, w02 = th ? r1.z : r0.w;
        a0 = fmaf(g0, w00, a0);
        a1 = fmaf(g0, w01, a1);
        a2 = fmaf(g0, w02, a2);
    }
    float s = a0 * a0 + a1 * a1 + a2 * a2;
    float f2 = s + __shfl_xor(s, 1, 64);  // sum over all 6 t
    float p = f2 + 1e-9f;
    p = p * p;
    float tot = p;
#pragma unroll
    for (int m = 1; m < 64; m <<= 1) tot += __shfl_xor(tot, m, 64);
    // each b counted twice (both th lanes) -> halve
    float nrm = sqrtf(0.5f * tot);
    float val = f2 * fast_rcp(nrm + 1.0f);
    if (th == 0) msg_in[(size_t)n * NB + b] = val;
}

// ---------------- K5: msg MLP (64 nodes/block, thread = 4 j x 8 nodes) ----------
__global__ __launch_bounds__(256) void k_msg(const float* __restrict__ msg_in,
                                             const float* __restrict__ w1,   // [32,128] orig
                                             const float* __restrict__ b1,
                                             const float* __restrict__ w2,   // [128,128] orig
                                             const float* __restrict__ b2,
                                             float* __restrict__ out) {
    __shared__ float mi[64 * 32];     // 8 KB input tile
    __shared__ float sh[64 * 128];    // 32 KB hidden tile
    int tid = threadIdx.x;
    int jq  = tid & 31;
    int ng  = tid >> 5;
    int j0  = jq * 4;
    int n0  = blockIdx.x * 64;

    // stage msg_in tile (64 nodes x 32 basis = 2048 floats)
    {
        const float4* srcp = (const float4*)msg_in;
        int base = n0 * 8;
        int maxi = N_NODES * 8 - 1;
#pragma unroll
        for (int r = 0; r < 2; r++) {
            int idx = base + r * 256 + tid;
            ((float4*)mi)[r * 256 + tid] = srcp[min(idx, maxi)];
        }
    }
    __syncthreads();

    float4 b1v = *(const float4*)&b1[j0];
    float h[8][4];
#pragma unroll
    for (int i = 0; i < 8; i++) {
        h[i][0] = b1v.x; h[i][1] = b1v.y; h[i][2] = b1v.z; h[i][3] = b1v.w;
    }
#pragma unroll
    for (int bb = 0; bb < 32; bb += 4) {
        float4 wv[4];
#pragma unroll
        for (int u = 0; u < 4; u++) wv[u] = *(const float4*)&w1[(bb + u) * 128 + j0];
#pragma unroll
        for (int i = 0; i < 8; i++) {
            float4 m4 = *(const float4*)&mi[(ng * 8 + i) * 32 + bb];
            h[i][0] = fmaf(m4.x, wv[0].x, h[i][0]);
            h[i][1] = fmaf(m4.x, wv[0].y, h[i][1]);
            h[i][2] = fmaf(m4.x, wv[0].z, h[i][2]);
            h[i][3] = fmaf(m4.x, wv[0].w, h[i][3]);
            h[i][0] = fmaf(m4.y, wv[1].x, h[i][0]);
            h[i][1] = fmaf(m4.y, wv[1].y, h[i][1]);
            h[i][2] = fmaf(m4.y, wv[1].z, h[i][2]);
            h[i][3] = fmaf(m4.y, wv[1].w, h[i][3]);
            h[i][0] = fmaf(m4.z, wv[2].x, h[i][0]);
            h[i][1] = fmaf(m4.z, wv[2].y, h[i][1]);
            h[i][2] = fmaf(m4.z, wv[2].z, h[i][2]);
            h[i][3] = fmaf(m4.z, wv[2].w, h[i][3]);
            h[i][0] = fmaf(m4.w, wv[3].x, h[i][0]);
            h[i][1] = fmaf(m4.w, wv[3].y, h[i][1]);
            h[i][2] = fmaf(m4.w, wv[3].z, h[i][2]);
            h[i][3] = fmaf(m4.w, wv[3].w, h[i][3]);
        }
    }
#pragma unroll
    for (int i = 0; i < 8; i++) {
        float4 sv = make_float4(silu_f(h[i][0]), silu_f(h[i][1]),
                                silu_f(h[i][2]), silu_f(h[i][3]));
        *(float4*)&sh[(ng * 8 + i) * 128 + j0] = sv;
    }
    __syncthreads();

    float4 b2v = *(const float4*)&b2[j0];
    float acc[8][4];
#pragma unroll
    for (int i = 0; i < 8; i++) {
        acc[i][0] = b2v.x; acc[i][1] = b2v.y; acc[i][2] = b2v.z; acc[i][3] = b2v.w;
    }
    for (int hb = 0; hb < 128; hb += 4) {
        float4 wv[4];
#pragma unroll
        for (int u = 0; u < 4; u++) wv[u] = *(const float4*)&w2[(hb + u) * 128 + j0];
#pragma unroll
        for (int i = 0; i < 8; i++) {
            float4 s4 = *(const float4*)&sh[(ng * 8 + i) * 128 + hb];
            acc[i][0] = fmaf(s4.x, wv[0].x, acc[i][0]);
            acc[i][1] = fmaf(s4.x, wv[0].y, acc[i][1]);
            acc[i][2] = fmaf(s4.x, wv[0].z, acc[i][2]);
            acc[i][3] = fmaf(s4.x, wv[0].w, acc[i][3]);
            acc[i][0] = fmaf(s4.y, wv[1].x, acc[i][0]);
            acc[i][1] = fmaf(s4.y, wv[1].y, acc[i][1]);
            acc[i][2] = fmaf(s4.y, wv[1].z, acc[i][2]);
            acc[i][3] = fmaf(s4.y, wv[1].w, acc[i][3]);
            acc[i][0] = fmaf(s4.z, wv[2].x, acc[i][0]);
            acc[i][1] = fmaf(s4.z, wv[2].y, acc[i][1]);
            acc[i][2] = fmaf(s4.z, wv[2].z, acc[i][2]);
            acc[i][3] = fmaf(s4.z, wv[2].w, acc[i][3]);
            acc[i][0] = fmaf(s4.w, wv[3].x, acc[i][0]);
            acc[i][1] = fmaf(s4.w, wv[3].y, acc[i][1]);
            acc[i][2] = fmaf(s4.w, wv[3].z, acc[i][2]);
            acc[i][3] = fmaf(s4.w, wv[3].w, acc[i][3]);
        }
    }
#pragma unroll
    for (int i = 0; i < 8; i++) {
        int n = n0 + ng * 8 + i;
        if (n < N_NODES) {
            *(float4*)&out[(size_t)n * 128 + j0] =
                make_float4(acc[i][0], acc[i][1], acc[i][2], acc[i][3]);
        }
    }
}

// ---------------- K2: filt (thread per edge, windowed gaussian) ----------------
// Outside |dis - offb| <= 2.05, g < 1.7e-9 -> filt == bias to ~1e-8 (threshold 1.2e-3).
// Row buffer lives in LDS (stride 36 words: 16B-aligned, conflict-free banks).
__global__ __launch_bounds__(256) void k_filt(const float* __restrict__ dis_vec,
                                              const float* __restrict__ fw1,
                                              const float* __restrict__ fw2,
                                              const float* __restrict__ fb2,
                                              float* __restrict__ out) {
    __shared__ float buf[256 * 36];   // 36 KB
    int tid = threadIdx.x;
    int e = blockIdx.x * 256 + tid;
    if (e >= N_EDGES) return;
    float dx = dis_vec[3 * e], dy = dis_vec[3 * e + 1], dz = dis_vec[3 * e + 2];
    float ax = dx + 1e-9f, ay = dy + 1e-9f, az = dz + 1e-9f;
    float dis = sqrtf(ax * ax + ay * ay + az * az);
    float x = dx + 1e-8f, y = dy + 1e-8f, z = dz + 1e-8f;
    // prefactor * PREF2, t order: (0,0,2),(0,1,1),(0,2,0),(1,0,1),(1,1,0),(2,0,0)
    float pre[6];
    pre[0] = z * z;      pre[1] = y * z * R2; pre[2] = y * y;
    pre[3] = x * z * R2; pre[4] = x * y * R2; pre[5] = x * x;
    float A = 0.f, B = 0.f;
#pragma unroll
    for (int t = 0; t < 6; t++) { A = fmaf(pre[t], pre[t], A); B += pre[t]; }
    float q[6];
#pragma unroll
    for (int tp = 0; tp < 6; tp++) {
        float s = 0.f;
#pragma unroll
        for (int t = 0; t < 6; t++) s = fmaf(pre[t], fw1[t * 6 + tp], s);
        q[tp] = s;
    }
    float bias = fb2[0];
    float w2r[6];
#pragma unroll
    for (int t = 0; t < 6; t++) w2r[t] = fw2[t];

    // init row to bias
    float* row = &buf[tid * 36];
    float4 b4v = make_float4(bias, bias, bias, bias);
#pragma unroll
    for (int r = 0; r < 8; r++) ((float4*)row)[r] = b4v;

    // windowed exact computation
    int b_lo = (int)ceilf((dis - HWIN) * INV_STEP);
#pragma unroll
    for (int k = 0; k < 14; k++) {
        int b = b_lo + k;
        float offb = (float)((double)b * STEP_D);
        float dd = dis - offb;
        float g = __expf(COEFF * dd * dd);
        // ||gauss + 1e-8||^2 over t, expanded: g^2*A + 2e-8*g*B + 6e-16
        float ns = fmaf(g * g, A, fmaf(2e-8f * g, B, 6e-16f));
        float rn = fast_rcp(sqrtf(ns) + 1.0f);
        float s = g * rn;
        float o = bias;
#pragma unroll
        for (int tp = 0; tp < 6; tp++) o = fmaf(silu_f(s * q[tp]), w2r[tp], o);
        if ((unsigned)b < 32u) row[b] = o;
    }

    // write back own row (coalesces through L2; full 128B line per edge)
    float4* orow = (float4*)(out + (size_t)e * 32);
#pragma unroll
    for (int r = 0; r < 8; r++) orow[r] = ((float4*)row)[r];
}

extern "C" void kernel_launch(void* const* d_in, const int* in_sizes, int n_in,
                              void* d_out, int out_size, void* d_ws, size_t ws_size,
                              hipStream_t stream) {
    (void)in_sizes; (void)n_in; (void)out_size; (void)ws_size;
    const float* feat    = (const float*)d_in[0];
    const float* dis_vec = (const float*)d_in[1];
    const float* cj_w1   = (const float*)d_in[2];
    const float* cj_b1   = (const float*)d_in[3];
    const float* cj_w2   = (const float*)d_in[4];
    const float* cj_b2   = (const float*)d_in[5];
    const float* msg_w1  = (const float*)d_in[6];
    const float* msg_b1  = (const float*)d_in[7];
    const float* msg_w2  = (const float*)d_in[8];
    const float* msg_b2  = (const float*)d_in[9];
    const float* filt_w1 = (const float*)d_in[10];
    const float* filt_w2 = (const float*)d_in[11];
    const float* filt_b2 = (const float*)d_in[12];
    const int*   src     = (const int*)d_in[13];
    const int*   dst     = (const int*)d_in[14];
    float* out = (float*)d_out;

    // workspace layout (elements), all 16B aligned
    float* ws     = (float*)d_ws;
    float* cj     = ws;                        // 50048
    float* msg_in = cj + 50048;                // 1600256
    int*   cnt    = (int*)(msg_in + 1600256);  // 50048
    int*   offs   = cnt + 50048;               // 50048
    int*   cursor = offs + 50048;              // 50048
    int*   bsum   = cursor + 50048;            // 64
    int*   bbase  = bsum + 64;                 // 64
    float* sedge  = (float*)(bbase + 64);      // 6400000 (25.6 MB)
    // total ~33 MB

    hipMemsetAsync(cnt, 0, N_NODES * sizeof(int), stream);

    k_cj<<<(N_NODES + 63) / 64, 256, 0, stream>>>(feat, cj_w1, cj_b1, cj_w2, cj_b2, cj);
    k_count<<<(N_EDGES + 255) / 256, 256, 0, stream>>>(src, cnt);
    k_scan1<<<49, 1024, 0, stream>>>(cnt, offs, bsum);
    k_scan2<<<1, 64, 0, stream>>>(bsum, bbase, 49);
    k_scan3<<<49, 1024, 0, stream>>>(offs, bbase, cursor);
    k_scatter<<<(N_EDGES + 255) / 256, 256, 0, stream>>>(src, dst, dis_vec, cj, cursor, sedge);
    k_agg<<<(N_NODES + 3) / 4, 256, 0, stream>>>(sedge, offs, cnt, msg_in);
    k_msg<<<(N_NODES + 63) / 64, 256, 0, stream>>>(msg_in, msg_w1, msg_b1, msg_w2, msg_b2, out);
    k_filt<<<(N_EDGES + 255) / 256, 256, 0, stream>>>(dis_vec, filt_w1, filt_w2, filt_b2,
                                                      out + (size_t)N_NODES * NA);
}